// Round 2
// baseline (432.207 us; speedup 1.0000x reference)
//
#include <hip/hip_runtime.h>
#include <math.h>

// Householder reflection + bias:  out = x - 2*(x·vhat)*vhat + bias
// Rewritten: c = 2*(x·v)/( (||v||+eps)^2 ),  out[j] = fma(-c, v[j], x[j]) + b[j]
//
// R2 structure: ONE WAVE PER ROW (no cross-wave barrier on the row path).
//  - 256-thread block = 4 waves = 4 rows; grid = batch/4 blocks.
//  - v staged into LDS once per block (16 KB) -> all v reads on-chip,
//    off the global critical path. Bias read from global in epilogue (L2-hit).
//  - Each thread holds its 16 float4 of x in registers (64 VGPRs, 16 global
//    loads in flight) so x is fetched from HBM exactly once.
//  - Reduction: 64-lane __shfl_xor butterfly (both sums), every lane ends
//    with the total -> no broadcast, no __syncthreads on the row path.

__global__ __launch_bounds__(256) void householder_kernel(
    const float* __restrict__ x,
    const float* __restrict__ v,
    const float* __restrict__ bias,
    float* __restrict__ out,
    int n)  // n == 4096; n/4 = 1024 float4 per row; 64 lanes * 16 float4
{
    __shared__ float4 vs[1024];            // 16 KB: v staged once per block

    const int tid = threadIdx.x;
    const float4* __restrict__ vp = (const float4*)v;

    #pragma unroll
    for (int k = 0; k < 4; ++k) {
        const int i = tid + (k << 8);
        vs[i] = vp[i];
    }
    __syncthreads();                       // only barrier: after v staging

    const int wid  = tid >> 6;             // wave 0..3
    const int lane = tid & 63;
    const int row  = (blockIdx.x << 2) + wid;

    const float4* __restrict__ xr   = (const float4*)(x + (size_t)row * n);
    const float4* __restrict__ bp   = (const float4*)bias;
    float4* __restrict__ outr       = (float4*)(out + (size_t)row * n);

    float4 xreg[16];
    float svv = 0.0f;
    float sxv = 0.0f;

    #pragma unroll
    for (int k = 0; k < 16; ++k) {
        const int idx = lane + (k << 6);   // wave covers 64 consecutive float4
        const float4 xx = xr[idx];
        const float4 vv = vs[idx];
        xreg[k] = xx;
        svv = fmaf(vv.x, vv.x, svv);
        svv = fmaf(vv.y, vv.y, svv);
        svv = fmaf(vv.z, vv.z, svv);
        svv = fmaf(vv.w, vv.w, svv);
        sxv = fmaf(xx.x, vv.x, sxv);
        sxv = fmaf(xx.y, vv.y, sxv);
        sxv = fmaf(xx.z, vv.z, sxv);
        sxv = fmaf(xx.w, vv.w, sxv);
    }

    // 64-lane butterfly reduce: every lane ends with the full sums.
    #pragma unroll
    for (int m = 32; m > 0; m >>= 1) {
        svv += __shfl_xor(svv, m, 64);
        sxv += __shfl_xor(sxv, m, 64);
    }

    const float inv = 1.0f / (sqrtf(svv) + 1e-14f);
    const float c = 2.0f * inv * inv * sxv;

    #pragma unroll
    for (int k = 0; k < 16; ++k) {
        const int idx = lane + (k << 6);
        const float4 vv = vs[idx];
        const float4 bb = bp[idx];         // L2-hit; independent of c
        const float4 xx = xreg[k];
        float4 o;
        o.x = fmaf(-c, vv.x, xx.x) + bb.x;
        o.y = fmaf(-c, vv.y, xx.y) + bb.y;
        o.z = fmaf(-c, vv.z, xx.z) + bb.z;
        o.w = fmaf(-c, vv.w, xx.w) + bb.w;
        outr[idx] = o;
    }
}

extern "C" void kernel_launch(void* const* d_in, const int* in_sizes, int n_in,
                              void* d_out, int out_size, void* d_ws, size_t ws_size,
                              hipStream_t stream) {
    (void)n_in; (void)d_ws; (void)ws_size; (void)out_size;
    const float* x    = (const float*)d_in[0];
    const float* v    = (const float*)d_in[1];
    const float* bias = (const float*)d_in[2];
    float* out = (float*)d_out;

    const int n = in_sizes[1];             // 4096 (vector is n x 1)
    const int batch = in_sizes[0] / n;     // 16384
    const int blocks = batch >> 2;         // 4 rows (waves) per block

    householder_kernel<<<blocks, 256, 0, stream>>>(x, v, bias, out, n);
}